// Round 1
// baseline (364.173 us; speedup 1.0000x reference)
//
#include <hip/hip_runtime.h>
#include <hip/hip_bf16.h>

// VectorQuantizer on MI355X (gfx950).
// GEMM-ified argmin: s_k = ||e_k||^2 - 2 x.e_k via bf16 MFMA 16x16x32,
// epilogue keeps running (best,idx) per row; fused gather/loss/transpose pass.

#define DIN 256
#define NCODES 1024
#define NTOT 33554432   // 32*256*64*64

typedef __attribute__((ext_vector_type(8))) short short8;
typedef __attribute__((ext_vector_type(4))) float float4v;
typedef __attribute__((ext_vector_type(4))) unsigned short ushort4v;

static __device__ __forceinline__ unsigned short f2bf(float f) {
  unsigned int u = __float_as_uint(f);
  unsigned int r = (u + 0x7fffu + ((u >> 16) & 1u)) >> 16;  // RNE
  return (unsigned short)r;
}

// ---- prep: codebook fp32 -> bf16 (ws) + per-code squared norms (ws) ----
__global__ void vq_prep(const float* __restrict__ e,
                        unsigned short* __restrict__ e_bf,
                        float* __restrict__ norms) {
  int wave = threadIdx.x >> 6, lane = threadIdx.x & 63;
  int k = blockIdx.x * 4 + wave;               // 256 blocks * 4 codes
  const float4v* src = (const float4v*)(e + k * DIN);
  float4v v = src[lane];                        // 64 lanes * 4 floats = 256
  float ss = v[0]*v[0] + v[1]*v[1] + v[2]*v[2] + v[3]*v[3];
  ushort4v pk;
  pk[0] = f2bf(v[0]); pk[1] = f2bf(v[1]); pk[2] = f2bf(v[2]); pk[3] = f2bf(v[3]);
  ((ushort4v*)(e_bf + k * DIN))[lane] = pk;
  #pragma unroll
  for (int m = 1; m < 64; m <<= 1) ss += __shfl_xor(ss, m, 64);
  if (lane == 0) norms[k] = ss;
}

// ---- main: per (b,h) line: 64 rows x 1024 codes argmin + output + loss ----
__global__ void __launch_bounds__(256, 2)
vq_main(const float* __restrict__ xin, const float* __restrict__ e_fp,
        const unsigned short* __restrict__ e_bf, const float* __restrict__ norms,
        float* __restrict__ out, float* __restrict__ loss_acc) {
  __shared__ char smem[65536];
  unsigned short* xs = (unsigned short*)smem;       // [64][256] bf16, swizzled
  unsigned short* es = (unsigned short*)smem;       // [128][256] bf16, swizzled
  float* vs  = (float*)(smem + 49152);              // [64][2] best vals
  int*   is_ = (int*)  (smem + 49664);              // [64][2] best idx
  int*   fi  = (int*)  (smem + 50176);              // [64] final idx
  float* rs  = (float*)(smem + 50432);              // [4] loss partials
  float* qs  = (float*)smem;                        // [128][65] fp32 transpose buf

  const int tid  = threadIdx.x;
  const int wave = tid >> 6, lane = tid & 63;
  const int m16  = lane & 15, quad = lane >> 4;
  const int wr   = wave >> 1, wc = wave & 1;        // wave tile: 32 rows x 64 cols
  const int b    = blockIdx.x >> 6, h = blockIdx.x & 63;
  const int base = b * 1048576 + h * 64;            // + d*4096 + w

  // ---- stage x (bf16, swizzled chunks of 8) ----
  {
    int w = lane;
    for (int q8 = 0; q8 < 8; ++q8) {
      int cc = q8 * 4 + wave;                       // chunk 0..31
      int d0 = cc * 8;
      short8 pk;
      #pragma unroll
      for (int ii = 0; ii < 8; ++ii) {
        float xv = xin[base + (d0 + ii) * 4096 + w];
        pk[ii] = (short)f2bf(xv);
      }
      *(short8*)(xs + w * 256 + 8 * (cc ^ (w & 7))) = pk;
    }
  }
  __syncthreads();

  // ---- preload all A fragments into registers (rows = wr*32 .. +31) ----
  short8 areg[16];
  #pragma unroll
  for (int i = 0; i < 2; ++i) {
    #pragma unroll
    for (int kk = 0; kk < 8; ++kk) {
      int r = wr * 32 + i * 16 + m16;
      int cc = kk * 4 + quad;
      areg[i * 8 + kk] = *(short8*)(xs + r * 256 + 8 * (cc ^ (r & 7)));
    }
  }
  __syncthreads();

  float bestv[2][4];
  int   besti[2][4];
  float4v acc[2][4];
  #pragma unroll
  for (int i = 0; i < 2; ++i)
    #pragma unroll
    for (int r = 0; r < 4; ++r) {
      bestv[i][r] = INFINITY; besti[i][r] = 0;
      acc[i][r] = (float4v)(0.0f);
    }

  // ---- 8 code tiles of 128 ----
  for (int ct = 0; ct < 8; ++ct) {
    int c0 = ct * 128;
    #pragma unroll
    for (int j = 0; j < 16; ++j) {                  // stage e tile: 128x256 bf16
      int f = j * 256 + tid;
      int kL = f >> 5, cc = f & 31;
      short8 vch = *(const short8*)(e_bf + (c0 + kL) * 256 + cc * 8);
      *(short8*)(es + kL * 256 + 8 * (cc ^ (kL & 7))) = vch;
    }
    __syncthreads();
    #pragma unroll
    for (int kk = 0; kk < 8; ++kk) {
      short8 bfr[4];
      #pragma unroll
      for (int j = 0; j < 4; ++j) {
        int cL = wc * 64 + j * 16 + m16;
        int cc = kk * 4 + quad;
        bfr[j] = *(short8*)(es + cL * 256 + 8 * (cc ^ (cL & 7)));
      }
      #pragma unroll
      for (int i = 0; i < 2; ++i)
        #pragma unroll
        for (int j = 0; j < 4; ++j)
          acc[i][j] = __builtin_amdgcn_mfma_f32_16x16x32_bf16(
              areg[i * 8 + kk], bfr[j], acc[i][j], 0, 0, 0);
    }
    // epilogue: fold norms, update running argmin (codes ascend -> strict <)
    #pragma unroll
    for (int j = 0; j < 4; ++j) {
      int col = c0 + wc * 64 + j * 16 + m16;
      float nj = norms[col];
      #pragma unroll
      for (int i = 0; i < 2; ++i) {
        #pragma unroll
        for (int r = 0; r < 4; ++r) {
          float s = nj - 2.0f * acc[i][j][r];
          if (s < bestv[i][r]) { bestv[i][r] = s; besti[i][r] = col; }
        }
        acc[i][j] = (float4v)(0.0f);
      }
    }
    __syncthreads();
  }

  // ---- cross-lane argmin over the 16 col-lanes (tie -> smaller idx) ----
  #pragma unroll
  for (int msk = 1; msk <= 8; msk <<= 1) {
    #pragma unroll
    for (int i = 0; i < 2; ++i)
      #pragma unroll
      for (int r = 0; r < 4; ++r) {
        float ov = __shfl_xor(bestv[i][r], msk, 64);
        int   oi = __shfl_xor(besti[i][r], msk, 64);
        if (ov < bestv[i][r] || (ov == bestv[i][r] && oi < besti[i][r])) {
          bestv[i][r] = ov; besti[i][r] = oi;
        }
      }
  }
  if (m16 == 0) {
    #pragma unroll
    for (int i = 0; i < 2; ++i)
      #pragma unroll
      for (int r = 0; r < 4; ++r) {
        int rl = wr * 32 + i * 16 + quad * 4 + r;
        vs [rl * 2 + wc] = bestv[i][r];
        is_[rl * 2 + wc] = besti[i][r];
      }
  }
  __syncthreads();
  if (tid < 64) {
    float v0 = vs[tid * 2], v1 = vs[tid * 2 + 1];
    fi[tid] = (v1 < v0) ? is_[tid * 2 + 1] : is_[tid * 2];   // tie -> lower codes (wc0)
  }
  __syncthreads();

  // ---- phase 2: gather exact fp32 e rows, transpose in LDS, write + loss ----
  float lsum = 0.0f;
  for (int h2 = 0; h2 < 2; ++h2) {
    #pragma unroll
    for (int j = 0; j < 8; ++j) {
      int f = j * 256 + tid;
      int w2 = f >> 5, cc = f & 31;
      int idx = fi[w2];
      float4v qv = *(const float4v*)(e_fp + idx * DIN + h2 * 128 + cc * 4);
      #pragma unroll
      for (int ii = 0; ii < 4; ++ii)
        qs[(cc * 4 + ii) * 65 + w2] = qv[ii];
    }
    __syncthreads();
    for (int dd = 0; dd < 32; ++dd) {
      int dL = wave * 32 + dd;
      int g = base + (h2 * 128 + dL) * 4096 + lane;
      float q  = qs[dL * 65 + lane];
      float xv = xin[g];
      out[1 + g] = q;
      float df = q - xv;
      lsum += df * df;
    }
    __syncthreads();
  }

  #pragma unroll
  for (int msk = 1; msk < 64; msk <<= 1) lsum += __shfl_xor(lsum, msk, 64);
  if (lane == 0) rs[wave] = lsum;
  __syncthreads();
  if (tid == 0) atomicAdd(loss_acc, rs[0] + rs[1] + rs[2] + rs[3]);
}

__global__ void vq_fin(const float* __restrict__ loss_acc,
                       const float* __restrict__ beta,
                       float* __restrict__ out) {
  out[0] = (1.0f + beta[0]) * loss_acc[0] / 33554432.0f;
}

extern "C" void kernel_launch(void* const* d_in, const int* in_sizes, int n_in,
                              void* d_out, int out_size, void* d_ws, size_t ws_size,
                              hipStream_t stream) {
  const float* xin  = (const float*)d_in[0];
  const float* emb  = (const float*)d_in[1];
  const float* beta = (const float*)d_in[2];
  float* out = (float*)d_out;
  float* loss_acc = (float*)d_ws;                                // 4 B
  float* norms = (float*)((char*)d_ws + 4096);                   // 4 KB
  unsigned short* e_bf = (unsigned short*)((char*)d_ws + 8192);  // 512 KB

  hipMemsetAsync(d_ws, 0, 4, stream);
  vq_prep<<<256, 256, 0, stream>>>(emb, e_bf, norms);
  vq_main<<<2048, 256, 0, stream>>>(xin, emb, e_bf, norms, out, loss_acc);
  vq_fin<<<1, 1, 0, stream>>>(loss_acc, beta, out);
}